// Round 8
// baseline (112.529 us; speedup 1.0000x reference)
//
#include <hip/hip_runtime.h>

#define NBINS 49
#define NCH   256
#define FH    256
#define FW    256
#define HWSZ  (FH * FW)

typedef float f4 __attribute__((ext_vector_type(4)));

// ============================================================================
// R8: single-pass, transpose ELIMINATED.
// Session record: R1 epilogue fix 199.6->71.0; R2 cond-gather -2.6x (loads must
// stay unconditional); R3 bitmap-predication lost; R4 deeper batching neutral
// (pool BW-bound); R5 slab-LLC lost; R6 in-kernel overlap lost. R7 confirmed
// two-pass floor = 71us. The transpose's 134MB write + ~50MB re-fetch is the
// remaining structural fat: this version reads x ONCE in CHW order (block =
// (batch, channel, y-quarter), 65-row strip in LDS) and gathers at LDS speed.
// Geometry is encoded once into 4B/bin codes (pass 0) -> no redundant trig.
// Bit-exactness: rx,ry in {0,0.5} exactly; codes reconstruct the IDENTICAL
// weight/offset arithmetic as the proven R1-R7 kernels (absmax 0.0).
// ============================================================================

// ---------------- pass 0: encode per-bin geometry into 4B codes ----------------
// bits: [7:0]=xl [15:8]=yt [16]=dxr [17]=dyb [18]=rx!=0 [19]=ry!=0
//       [20]=zlt [21]=zrt [22]=zrb [23]=zlb   (z* = weight-nonzero/validity)
__global__ __launch_bounds__(64) void encode_geom(
    const float* __restrict__ boxes,   // (1024, 5)
    unsigned*    __restrict__ codes)   // (1024, 49)
{
    const int roi = blockIdx.x;
    const int tid = threadIdx.x;
    if (tid >= NBINS) return;
    const float* bx = boxes + roi * 5;
    // --- exact f32 replication of reference geometry (absmax=0.0, R1-R7) ---
    float cx  = __fmul_rn(bx[0], 0.25f);
    float cy  = __fmul_rn(bx[1], 0.25f);
    float w   = __fmul_rn(bx[2], 0.25f);
    float h   = __fmul_rn(bx[3], 0.25f);
    float ang = __fmul_rn(bx[4], 0.017453292519943295f);
    float ca = (float)cos((double)ang);
    float sa = (float)sin((double)ang);
    float Sx = __fdiv_rn(w, 7.0f);
    float Sy = __fdiv_rn(h, 7.0f);
    const float dx = -3.5f, dy = -3.5f;
    float M00 = __fmul_rn(ca, Sx);
    float M01 = __fmul_rn(sa, Sy);
    float M02 = __fadd_rn(__fadd_rn(__fmul_rn(M00, dx), __fmul_rn(M01, dy)), cx);
    float nsa = -sa;
    float M10 = __fmul_rn(nsa, Sx);
    float M11 = __fmul_rn(ca, Sy);
    float M12 = __fadd_rn(__fadd_rn(__fmul_rn(M10, dx), __fmul_rn(M11, dy)), cy);

    int ph = tid / 7, pw = tid % 7;
    float minX = 1e30f, maxX = -1e30f, minY = 1e30f, maxY = -1e30f;
    #pragma unroll
    for (int o0 = 0; o0 < 2; ++o0) {
        #pragma unroll
        for (int o1 = 0; o1 < 2; ++o1) {
            float px = (float)(pw + o0);
            float py = (float)(ph + o1);
            float Xc = __fadd_rn(__fadd_rn(__fmul_rn(M00, px), __fmul_rn(M01, py)), M02);
            float Yc = __fadd_rn(__fadd_rn(__fmul_rn(M10, px), __fmul_rn(M11, py)), M12);
            minX = fminf(minX, Xc); maxX = fmaxf(maxX, Xc);
            minY = fminf(minY, Yc); maxY = fmaxf(maxY, Yc);
        }
    }
    float leftMost   = fmaxf(rintf(minX), 0.0f);
    float rightMost  = fminf(rintf(maxX), (float)(FW - 1));
    float topMost    = fmaxf(rintf(minY), 0.0f);
    float bottomMost = fminf(rintf(maxY), (float)(FH - 1));
    float bcx = __fmul_rn(__fadd_rn(leftMost, rightMost), 0.5f);
    float bcy = __fmul_rn(__fadd_rn(topMost, bottomMost), 0.5f);
    float fl = floorf(bcx), ft = floorf(bcy);
    int l   = (int)fl;
    int r   = (int)ceilf(bcx);
    int t   = (int)ft;
    int btm = (int)ceilf(bcy);
    float rx = __fsub_rn(bcx, fl);   // exactly 0.0 or 0.5
    float ry = __fsub_rn(bcy, ft);

    bool vl = (unsigned)l   < (unsigned)FW;
    bool vr = (unsigned)r   < (unsigned)FW;
    bool vt = (unsigned)t   < (unsigned)FH;
    bool vb = (unsigned)btm < (unsigned)FH;
    int xl = min(max(l, 0), FW - 1), xr = min(max(r, 0), FW - 1);
    int yt = min(max(t, 0), FH - 1), yb = min(max(btm, 0), FH - 1);
    // xr-xl, yb-yt in {0,1} (pre-clamp diff in {0,1}, clamping can only collapse)

    unsigned code = (unsigned)xl
                  | ((unsigned)yt << 8)
                  | ((unsigned)(xr - xl) << 16)
                  | ((unsigned)(yb - yt) << 17)
                  | ((rx != 0.0f ? 1u : 0u) << 18)
                  | ((ry != 0.0f ? 1u : 0u) << 19)
                  | (((vt && vl) ? 1u : 0u) << 20)
                  | (((vt && vr) ? 1u : 0u) << 21)
                  | (((vb && vr) ? 1u : 0u) << 22)
                  | (((vb && vl) ? 1u : 0u) << 23);
    codes[roi * NBINS + tid] = code;
}

// ---------------- pass 1: pool, block = (batch, channel, y-quarter) ----------------
// Loads rows [64q, 64q+64] of plane (b,c) into LDS (coalesced f4, x read ONCE),
// then serves every bin whose top row yt lies in this quarter (yb <= yt+1 is
// always resident). Each (roi,c,bin) is owned by exactly one quarter.
__global__ __launch_bounds__(512) void rroi_pool_quarter(
    const float*    __restrict__ x,      // (2, 256, 256, 256)
    const unsigned* __restrict__ codes,  // (1024, 49)
    float*          __restrict__ out)    // (1024, 256, 7, 7)
{
    __shared__ float plane[65 * FW];     // 66,560 B -> 2 blocks/CU

    const int flat = blockIdx.x;         // 2048 = 2b * 256c * 4q
    const int q = flat & 3;
    const int c = (flat >> 2) & 255;
    const int b = flat >> 10;
    const int y0 = q * 64;
    const int nf4 = (q == 3) ? (64 * FW / 4) : (65 * FW / 4);  // q3: rows 192..255

    // ---- fill: contiguous 65-row strip, fully coalesced ----
    const f4* src4 = (const f4*)(x + ((size_t)(b * NCH + c) * HWSZ + (size_t)y0 * FW));
    f4* p4 = (f4*)plane;
    for (int j = threadIdx.x; j < nf4; j += 512)
        p4[j] = __builtin_nontemporal_load(src4 + j);
    __syncthreads();

    // ---- gather: scan all (roi,bin) codes of this batch, serve owned bins ----
    const unsigned* cb = codes + b * 512 * NBINS;
    for (int i = threadIdx.x; i < 512 * NBINS; i += 512) {
        const unsigned code = cb[i];                    // wave: 64 consecutive -> coalesced
        const int yt = (int)((code >> 8) & 255u);
        if ((yt >> 6) != q) continue;                   // not this quarter's bin
        const int roi_l = (int)((unsigned)i / (unsigned)NBINS);   // magic-mul div
        const int bin   = i - roi_l * NBINS;
        const int xl  = (int)(code & 255u);
        const int dxr = (int)((code >> 16) & 1u);
        const int dyb = (int)((code >> 17) & 1u);
        const float rx = (code & (1u << 18)) ? 0.5f : 0.0f;   // exact reconstruction
        const float ry = (code & (1u << 19)) ? 0.5f : 0.0f;

        const int rbase = (yt - y0) * FW + xl;
        const float lt = plane[rbase];
        const float rt = plane[rbase + dxr];
        const float lb = plane[rbase + dyb * FW];
        const float rb = plane[rbase + dyb * FW + dxr];

        // verbatim weight arithmetic from the proven kernels (bit-exact)
        const float w_lt = (1.0f - rx) * (1.0f - ry);
        const float w_rt = rx * (1.0f - ry);
        const float w_rb = rx * ry;
        const float w_lb = (1.0f - rx) * ry;
        const float wlt = (code & (1u << 20)) ? w_lt : 0.0f;
        const float wrt = (code & (1u << 21)) ? w_rt : 0.0f;
        const float wrb = (code & (1u << 22)) ? w_rb : 0.0f;
        const float wlb = (code & (1u << 23)) ? w_lb : 0.0f;

        const float v = lt * wlt + rt * wrt + rb * wrb + lb * wlb;
        out[((size_t)(b * 512 + roi_l) * NCH + c) * NBINS + bin] = fmaxf(v, 0.0f);
    }
}

// ---------------- fallback: proven R0 single-pass kernel ----------------
__global__ __launch_bounds__(256) void rroi_pool_chw(
    const float* __restrict__ x, const float* __restrict__ boxes, float* __restrict__ out)
{
    __shared__ int   s_l[NBINS], s_r[NBINS], s_t[NBINS], s_b[NBINS];
    __shared__ float s_rx[NBINS], s_ry[NBINS];
    const int roi = blockIdx.x, tid = threadIdx.x, b = roi >> 9;
    if (tid < NBINS) {
        const float* bx = boxes + roi * 5;
        float cx  = __fmul_rn(bx[0], 0.25f);
        float cy  = __fmul_rn(bx[1], 0.25f);
        float w   = __fmul_rn(bx[2], 0.25f);
        float h   = __fmul_rn(bx[3], 0.25f);
        float ang = __fmul_rn(bx[4], 0.017453292519943295f);
        float ca = (float)cos((double)ang);
        float sa = (float)sin((double)ang);
        float Sx = __fdiv_rn(w, 7.0f);
        float Sy = __fdiv_rn(h, 7.0f);
        const float dx = -3.5f, dy = -3.5f;
        float M00 = __fmul_rn(ca, Sx);
        float M01 = __fmul_rn(sa, Sy);
        float M02 = __fadd_rn(__fadd_rn(__fmul_rn(M00, dx), __fmul_rn(M01, dy)), cx);
        float nsa = -sa;
        float M10 = __fmul_rn(nsa, Sx);
        float M11 = __fmul_rn(ca, Sy);
        float M12 = __fadd_rn(__fadd_rn(__fmul_rn(M10, dx), __fmul_rn(M11, dy)), cy);
        int ph = tid / 7, pw = tid % 7;
        float minX = 1e30f, maxX = -1e30f, minY = 1e30f, maxY = -1e30f;
        #pragma unroll
        for (int o0 = 0; o0 < 2; ++o0)
            #pragma unroll
            for (int o1 = 0; o1 < 2; ++o1) {
                float px = (float)(pw + o0);
                float py = (float)(ph + o1);
                float Xc = __fadd_rn(__fadd_rn(__fmul_rn(M00, px), __fmul_rn(M01, py)), M02);
                float Yc = __fadd_rn(__fadd_rn(__fmul_rn(M10, px), __fmul_rn(M11, py)), M12);
                minX = fminf(minX, Xc); maxX = fmaxf(maxX, Xc);
                minY = fminf(minY, Yc); maxY = fmaxf(maxY, Yc);
            }
        float leftMost   = fmaxf(rintf(minX), 0.0f);
        float rightMost  = fminf(rintf(maxX), (float)(FW - 1));
        float topMost    = fmaxf(rintf(minY), 0.0f);
        float bottomMost = fminf(rintf(maxY), (float)(FH - 1));
        float bcx = __fmul_rn(__fadd_rn(leftMost, rightMost), 0.5f);
        float bcy = __fmul_rn(__fadd_rn(topMost, bottomMost), 0.5f);
        float fl = floorf(bcx), ft = floorf(bcy);
        s_l[tid] = (int)fl;  s_r[tid] = (int)ceilf(bcx);
        s_t[tid] = (int)ft;  s_b[tid] = (int)ceilf(bcy);
        s_rx[tid] = __fsub_rn(bcx, fl);
        s_ry[tid] = __fsub_rn(bcy, ft);
    }
    __syncthreads();
    const float* featb = x + (size_t)b * NCH * HWSZ;
    float* outr = out + (size_t)roi * NCH * NBINS;
    for (int i = tid; i < NCH * NBINS; i += 256) {
        int c = i / NBINS, bin = i - c * NBINS;
        int l = s_l[bin], r = s_r[bin], t = s_t[bin], btm = s_b[bin];
        float rx = s_rx[bin], ry = s_ry[bin];
        const float* fc = featb + (size_t)c * HWSZ;
        bool vl = (unsigned)l < (unsigned)FW, vr = (unsigned)r < (unsigned)FW;
        bool vt = (unsigned)t < (unsigned)FH, vb = (unsigned)btm < (unsigned)FH;
        int lc = min(max(l, 0), FW - 1), rc = min(max(r, 0), FW - 1);
        int tc = min(max(t, 0), FH - 1), bc = min(max(btm, 0), FH - 1);
        float lt = (vt && vl) ? fc[tc * FW + lc] : 0.0f;
        float rt = (vt && vr) ? fc[tc * FW + rc] : 0.0f;
        float lb = (vb && vl) ? fc[bc * FW + lc] : 0.0f;
        float rb = (vb && vr) ? fc[bc * FW + rc] : 0.0f;
        float w_lt = (1.0f - rx) * (1.0f - ry);
        float w_rt = rx * (1.0f - ry);
        float w_rb = rx * ry;
        float w_lb = (1.0f - rx) * ry;
        float v = lt * w_lt + rt * w_rt + rb * w_rb + lb * w_lb;
        outr[i] = fmaxf(v, 0.0f);
    }
}

extern "C" void kernel_launch(void* const* d_in, const int* in_sizes, int n_in,
                              void* d_out, int out_size, void* d_ws, size_t ws_size,
                              hipStream_t stream) {
    const float* x     = (const float*)d_in[0];
    const float* boxes = (const float*)d_in[1];
    float* out = (float*)d_out;
    (void)in_sizes; (void)n_in; (void)out_size;

    const size_t need_codes = (size_t)1024 * NBINS * sizeof(unsigned);  // ~200 KB
    if (ws_size >= need_codes) {
        unsigned* codes = (unsigned*)d_ws;
        encode_geom<<<dim3(1024), dim3(64), 0, stream>>>(boxes, codes);
        rroi_pool_quarter<<<dim3(2048), dim3(512), 0, stream>>>(x, codes, out);
    } else {
        rroi_pool_chw<<<dim3(1024), dim3(256), 0, stream>>>(x, boxes, out);
    }
}

// Round 9
// 84.855 us; speedup vs baseline: 1.3261x; 1.3261x over previous
//
#include <hip/hip_runtime.h>

#define NBINS 49
#define NCH   256
#define FH    256
#define FW    256
#define HWSZ  (FH * FW)
#define PLD   260            // padded LDS row stride (floats): 16B-aligned, bank-skewed
#define BCAP  25088          // bucket capacity = 512 rois * 49 bins (worst case)

typedef float f4 __attribute__((ext_vector_type(4)));

// ============================================================================
// R9: single-pass + bucketed codes.
// R8 LESSON (counters): single-pass killed HBM traffic (537->139 MB) but the
// per-block scan of ALL 25088 codes (75% discarded, divergent skip, magic-div)
// made it VALU/scan-bound at 111us. R9 buckets codes by (batch, y-quarter) in
// the encode pass -> pool blocks iterate ONLY owned entries (4x fewer
// lane-iters, zero skip-divergence). Geometry arithmetic stays the verbatim
// absmax=0.0 replication; bucket order is nondeterministic but each output is
// written exactly once with a deterministic value.
// ============================================================================

// ---------------- pass 0: encode + bucket ----------------
// code bits: [7:0]=xl [15:8]=yt [16]=dxr [17]=dyb [18]=rx!=0 [19]=ry!=0
//            [20]=zlt [21]=zrt [22]=zrb [23]=zlb
// entry: .x = code, .y = (roi_local<<6)|bin
__global__ __launch_bounds__(64) void encode_geom(
    const float* __restrict__ boxes,   // (1024, 5)
    int*         __restrict__ cnts,    // (8) per-(batch,quarter) counts
    uint2*       __restrict__ buckets) // (8, BCAP)
{
    const int roi = blockIdx.x;
    const int tid = threadIdx.x;
    if (tid >= NBINS) return;
    const int b = roi >> 9;
    const float* bx = boxes + roi * 5;
    // --- exact f32 replication of reference geometry (absmax=0.0, R1-R8) ---
    float cx  = __fmul_rn(bx[0], 0.25f);
    float cy  = __fmul_rn(bx[1], 0.25f);
    float w   = __fmul_rn(bx[2], 0.25f);
    float h   = __fmul_rn(bx[3], 0.25f);
    float ang = __fmul_rn(bx[4], 0.017453292519943295f);
    float ca = (float)cos((double)ang);
    float sa = (float)sin((double)ang);
    float Sx = __fdiv_rn(w, 7.0f);
    float Sy = __fdiv_rn(h, 7.0f);
    const float dx = -3.5f, dy = -3.5f;
    float M00 = __fmul_rn(ca, Sx);
    float M01 = __fmul_rn(sa, Sy);
    float M02 = __fadd_rn(__fadd_rn(__fmul_rn(M00, dx), __fmul_rn(M01, dy)), cx);
    float nsa = -sa;
    float M10 = __fmul_rn(nsa, Sx);
    float M11 = __fmul_rn(ca, Sy);
    float M12 = __fadd_rn(__fadd_rn(__fmul_rn(M10, dx), __fmul_rn(M11, dy)), cy);

    int ph = tid / 7, pw = tid % 7;
    float minX = 1e30f, maxX = -1e30f, minY = 1e30f, maxY = -1e30f;
    #pragma unroll
    for (int o0 = 0; o0 < 2; ++o0) {
        #pragma unroll
        for (int o1 = 0; o1 < 2; ++o1) {
            float px = (float)(pw + o0);
            float py = (float)(ph + o1);
            float Xc = __fadd_rn(__fadd_rn(__fmul_rn(M00, px), __fmul_rn(M01, py)), M02);
            float Yc = __fadd_rn(__fadd_rn(__fmul_rn(M10, px), __fmul_rn(M11, py)), M12);
            minX = fminf(minX, Xc); maxX = fmaxf(maxX, Xc);
            minY = fminf(minY, Yc); maxY = fmaxf(maxY, Yc);
        }
    }
    float leftMost   = fmaxf(rintf(minX), 0.0f);
    float rightMost  = fminf(rintf(maxX), (float)(FW - 1));
    float topMost    = fmaxf(rintf(minY), 0.0f);
    float bottomMost = fminf(rintf(maxY), (float)(FH - 1));
    float bcx = __fmul_rn(__fadd_rn(leftMost, rightMost), 0.5f);
    float bcy = __fmul_rn(__fadd_rn(topMost, bottomMost), 0.5f);
    float fl = floorf(bcx), ft = floorf(bcy);
    int l   = (int)fl;
    int r   = (int)ceilf(bcx);
    int t   = (int)ft;
    int btm = (int)ceilf(bcy);
    float rx = __fsub_rn(bcx, fl);   // exactly 0.0 or 0.5
    float ry = __fsub_rn(bcy, ft);

    bool vl = (unsigned)l   < (unsigned)FW;
    bool vr = (unsigned)r   < (unsigned)FW;
    bool vt = (unsigned)t   < (unsigned)FH;
    bool vb = (unsigned)btm < (unsigned)FH;
    int xl = min(max(l, 0), FW - 1), xr = min(max(r, 0), FW - 1);
    int yt = min(max(t, 0), FH - 1), yb = min(max(btm, 0), FH - 1);
    // xr-xl, yb-yt in {0,1}: pre-clamp diff in {0,1}; clamping only collapses.

    unsigned code = (unsigned)xl
                  | ((unsigned)yt << 8)
                  | ((unsigned)(xr - xl) << 16)
                  | ((unsigned)(yb - yt) << 17)
                  | ((rx != 0.0f ? 1u : 0u) << 18)
                  | ((ry != 0.0f ? 1u : 0u) << 19)
                  | (((vt && vl) ? 1u : 0u) << 20)
                  | (((vt && vr) ? 1u : 0u) << 21)
                  | (((vb && vr) ? 1u : 0u) << 22)
                  | (((vb && vl) ? 1u : 0u) << 23);

    const int q = yt >> 6;
    const int roi_l = roi & 511;
    // wave-level aggregated append: ONE atomicAdd per quarter per ROI-wave.
    #pragma unroll
    for (int qq = 0; qq < 4; ++qq) {
        unsigned long long m = __ballot(q == qq);
        if (q == qq) {
            const int leader = (int)(__ffsll((long long)m) - 1);
            int base = 0;
            if (tid == leader)
                base = atomicAdd(&cnts[b * 4 + qq], __popcll(m));
            base = __shfl(base, leader);
            const int pos = __popcll(m & ((1ull << tid) - 1ull));
            uint2 e;
            e.x = code;
            e.y = ((unsigned)roi_l << 6) | (unsigned)tid;
            buckets[(size_t)(b * 4 + qq) * BCAP + base + pos] = e;
        }
    }
}

// ---------------- pass 1: pool, block = (batch, channel, y-quarter) ----------------
// Loads rows [64q, 64q+64] of plane (b,c) into padded LDS (x read ONCE,
// coalesced f4), then processes ONLY this quarter's bucket entries.
__global__ __launch_bounds__(512) void rroi_pool_bucket(
    const float* __restrict__ x,       // (2, 256, 256, 256)
    const int*   __restrict__ cnts,    // (8)
    const uint2* __restrict__ buckets, // (8, BCAP)
    float*       __restrict__ out)     // (1024, 256, 7, 7)
{
    __shared__ float plane[65 * PLD];  // 67,600 B -> 2 blocks/CU

    const int flat = blockIdx.x;       // 2048 = 2b * 256c * 4q
    const int q = flat & 3;
    const int c = (flat >> 2) & 255;
    const int b = flat >> 10;
    const int y0 = q * 64;
    const int nrows = (q == 3) ? 64 : 65;     // q3: rows 192..255 (yt=255 => dyb=0)
    const int nf4 = nrows * (FW / 4);

    // ---- fill: contiguous strip, coalesced f4 loads; padded LDS rows ----
    const f4* src4 = (const f4*)(x + ((size_t)(b * NCH + c) * HWSZ + (size_t)y0 * FW));
    f4* p4 = (f4*)plane;               // row stride PLD floats = 65 f4 (16B-aligned)
    for (int j = threadIdx.x; j < nf4; j += 512) {
        const int row = j >> 6, c4 = j & 63;
        p4[row * (PLD / 4) + c4] = __builtin_nontemporal_load(src4 + j);
    }
    __syncthreads();

    // ---- process ONLY owned entries: no skip-divergence, no div/mod ----
    const int cnt = cnts[b * 4 + q];
    const uint2* bk = buckets + (size_t)(b * 4 + q) * BCAP;
    const size_t outBase = (size_t)b * 512 * (NCH * NBINS) + (size_t)c * NBINS;

    for (int i = threadIdx.x; i < cnt; i += 512) {
        const uint2 e = bk[i];                     // coalesced 8B
        const unsigned code = e.x;
        const unsigned rb_  = e.y;
        const int xl   = (int)(code & 255u);
        const int ytL  = (int)((code >> 8) & 255u) - y0;   // 0..63
        const int dxr  = (int)((code >> 16) & 1u);
        const int dyb  = (int)((code >> 17) & 1u);
        const float rx = (code & (1u << 18)) ? 0.5f : 0.0f;  // exact reconstruction
        const float ry = (code & (1u << 19)) ? 0.5f : 0.0f;

        const int rbase = ytL * PLD + xl;
        const float lt = plane[rbase];
        const float rt = plane[rbase + dxr];
        const float lb = plane[rbase + dyb * PLD];
        const float rb = plane[rbase + dyb * PLD + dxr];

        // verbatim weight arithmetic from the proven kernels (bit-exact)
        const float w_lt = (1.0f - rx) * (1.0f - ry);
        const float w_rt = rx * (1.0f - ry);
        const float w_rb = rx * ry;
        const float w_lb = (1.0f - rx) * ry;
        const float wlt = (code & (1u << 20)) ? w_lt : 0.0f;
        const float wrt = (code & (1u << 21)) ? w_rt : 0.0f;
        const float wrb = (code & (1u << 22)) ? w_rb : 0.0f;
        const float wlb = (code & (1u << 23)) ? w_lb : 0.0f;

        const float v = lt * wlt + rt * wrt + rb * wrb + lb * wlb;
        const unsigned roff = (rb_ >> 6) * (unsigned)(NCH * NBINS) + (rb_ & 63u);
        out[outBase + roff] = fmaxf(v, 0.0f);
    }
}

// ---------------- fallback: proven R0 single-pass kernel ----------------
__global__ __launch_bounds__(256) void rroi_pool_chw(
    const float* __restrict__ x, const float* __restrict__ boxes, float* __restrict__ out)
{
    __shared__ int   s_l[NBINS], s_r[NBINS], s_t[NBINS], s_b[NBINS];
    __shared__ float s_rx[NBINS], s_ry[NBINS];
    const int roi = blockIdx.x, tid = threadIdx.x, b = roi >> 9;
    if (tid < NBINS) {
        const float* bx = boxes + roi * 5;
        float cx  = __fmul_rn(bx[0], 0.25f);
        float cy  = __fmul_rn(bx[1], 0.25f);
        float w   = __fmul_rn(bx[2], 0.25f);
        float h   = __fmul_rn(bx[3], 0.25f);
        float ang = __fmul_rn(bx[4], 0.017453292519943295f);
        float ca = (float)cos((double)ang);
        float sa = (float)sin((double)ang);
        float Sx = __fdiv_rn(w, 7.0f);
        float Sy = __fdiv_rn(h, 7.0f);
        const float dx = -3.5f, dy = -3.5f;
        float M00 = __fmul_rn(ca, Sx);
        float M01 = __fmul_rn(sa, Sy);
        float M02 = __fadd_rn(__fadd_rn(__fmul_rn(M00, dx), __fmul_rn(M01, dy)), cx);
        float nsa = -sa;
        float M10 = __fmul_rn(nsa, Sx);
        float M11 = __fmul_rn(ca, Sy);
        float M12 = __fadd_rn(__fadd_rn(__fmul_rn(M10, dx), __fmul_rn(M11, dy)), cy);
        int ph = tid / 7, pw = tid % 7;
        float minX = 1e30f, maxX = -1e30f, minY = 1e30f, maxY = -1e30f;
        #pragma unroll
        for (int o0 = 0; o0 < 2; ++o0)
            #pragma unroll
            for (int o1 = 0; o1 < 2; ++o1) {
                float px = (float)(pw + o0);
                float py = (float)(ph + o1);
                float Xc = __fadd_rn(__fadd_rn(__fmul_rn(M00, px), __fmul_rn(M01, py)), M02);
                float Yc = __fadd_rn(__fadd_rn(__fmul_rn(M10, px), __fmul_rn(M11, py)), M12);
                minX = fminf(minX, Xc); maxX = fmaxf(maxX, Xc);
                minY = fminf(minY, Yc); maxY = fmaxf(maxY, Yc);
            }
        float leftMost   = fmaxf(rintf(minX), 0.0f);
        float rightMost  = fminf(rintf(maxX), (float)(FW - 1));
        float topMost    = fmaxf(rintf(minY), 0.0f);
        float bottomMost = fminf(rintf(maxY), (float)(FH - 1));
        float bcx = __fmul_rn(__fadd_rn(leftMost, rightMost), 0.5f);
        float bcy = __fmul_rn(__fadd_rn(topMost, bottomMost), 0.5f);
        float fl = floorf(bcx), ft = floorf(bcy);
        s_l[tid] = (int)fl;  s_r[tid] = (int)ceilf(bcx);
        s_t[tid] = (int)ft;  s_b[tid] = (int)ceilf(bcy);
        s_rx[tid] = __fsub_rn(bcx, fl);
        s_ry[tid] = __fsub_rn(bcy, ft);
    }
    __syncthreads();
    const float* featb = x + (size_t)b * NCH * HWSZ;
    float* outr = out + (size_t)roi * NCH * NBINS;
    for (int i = tid; i < NCH * NBINS; i += 256) {
        int c = i / NBINS, bin = i - c * NBINS;
        int l = s_l[bin], r = s_r[bin], t = s_t[bin], btm = s_b[bin];
        float rx = s_rx[bin], ry = s_ry[bin];
        const float* fc = featb + (size_t)c * HWSZ;
        bool vl = (unsigned)l < (unsigned)FW, vr = (unsigned)r < (unsigned)FW;
        bool vt = (unsigned)t < (unsigned)FH, vb = (unsigned)btm < (unsigned)FH;
        int lc = min(max(l, 0), FW - 1), rc = min(max(r, 0), FW - 1);
        int tc = min(max(t, 0), FH - 1), bc = min(max(btm, 0), FH - 1);
        float lt = (vt && vl) ? fc[tc * FW + lc] : 0.0f;
        float rt = (vt && vr) ? fc[tc * FW + rc] : 0.0f;
        float lb = (vb && vl) ? fc[bc * FW + lc] : 0.0f;
        float rb = (vb && vr) ? fc[bc * FW + rc] : 0.0f;
        float w_lt = (1.0f - rx) * (1.0f - ry);
        float w_rt = rx * (1.0f - ry);
        float w_rb = rx * ry;
        float w_lb = (1.0f - rx) * ry;
        float v = lt * w_lt + rt * w_rt + rb * w_rb + lb * w_lb;
        outr[i] = fmaxf(v, 0.0f);
    }
}

extern "C" void kernel_launch(void* const* d_in, const int* in_sizes, int n_in,
                              void* d_out, int out_size, void* d_ws, size_t ws_size,
                              hipStream_t stream) {
    const float* x     = (const float*)d_in[0];
    const float* boxes = (const float*)d_in[1];
    float* out = (float*)d_out;
    (void)in_sizes; (void)n_in; (void)out_size;

    // ws layout: [0,32) counters (8 ints), [256, 256+8*BCAP*8) buckets (~1.6 MB)
    const size_t need = 256 + (size_t)8 * BCAP * sizeof(uint2);
    if (ws_size >= need) {
        int*   cnts    = (int*)d_ws;
        uint2* buckets = (uint2*)((char*)d_ws + 256);
        hipMemsetAsync(cnts, 0, 32, stream);
        encode_geom<<<dim3(1024), dim3(64), 0, stream>>>(boxes, cnts, buckets);
        rroi_pool_bucket<<<dim3(2048), dim3(512), 0, stream>>>(x, cnts, buckets, out);
    } else {
        rroi_pool_chw<<<dim3(1024), dim3(256), 0, stream>>>(x, boxes, out);
    }
}